// Round 12
// baseline (144.515 us; speedup 1.0000x reference)
//
#include <hip/hip_runtime.h>
#include <math.h>

// S4 DPLR kernel + batched causal convolution via custom packed-real FFTs.
//
//  A) s4_khat_kernel : wave-per-l Cauchy sum (byte-identical, verified).
//  B) s4_tabs_kernel : LDS-staged Dirichlet odd bins + S_K + sigma-permuted
//       pair tables (byte-identical v4/v9 form, verified; radix-8 sigma).
//  C) s4_conv_kernel v13 : v9 structure (TPB=512, packed fp32, linear
//       swizzled addresses, INLINE pointwise — verified stable rounds 8-10,
//       conv ~47us) + wtree8 depth-3 stage twiddles (verified in v11's full
//       pass). v12's batched/unrolled table pointwise REVERTED: it diverged
//       post-timing (absmax 170 after graph replays, fresh launches stably
//       wrong) despite being semantically equivalent to v11 by address-set
//       analysis — unexplained => reverted per rigor discipline. Tw/Taj
//       tables dropped entirely; workspace back to the v4-verified layout.
//
// LDS addresses go through SW(x) = x ^ ((x>>4)&15) (verified swizzle), made
// affine per stage: t=1024 -> 1 base + imms; t=128 -> 2 bases (q parity);
// t=16 -> 8 addrs at 2 ops; tail odd addr = even addr ^ 1.

#define TPB 512

typedef float cpx __attribute__((ext_vector_type(2)));

__device__ __forceinline__ cpx mkc(float x, float y){ cpx r; r.x = x; r.y = y; return r; }

__device__ __forceinline__ int SW(int x){ return x ^ ((x >> 4) & 15); }

// complex mul: a*b = a*b.x + (-a.y,a.x)*b.y  (v_pk_mul + v_pk_fma)
__device__ __forceinline__ cpx cmulf(cpx a, cpx b){
  cpx m = mkc(-a.y, a.x);
  return a * b.x + m * b.y;
}
// a * conj(b)
__device__ __forceinline__ cpx cmulcf(cpx a, cpx b){
  cpx m = mkc(a.y, -a.x);
  return a * b.x + m * b.y;
}
template<int SGN>
__device__ __forceinline__ cpx muli(cpx v){
  return (SGN > 0) ? mkc(-v.y, v.x) : mkc(v.y, -v.x);
}

template<int SGN>   // -1: forward DFT8; +1: conj (unscaled inverse)
__device__ __forceinline__ void dft8(const cpx* a, cpx* X){
  const float C  = 0.70710678118654752f;
  const float SC = (SGN > 0) ? C : -C;
  cpx e0=a[0]+a[4], e1=a[0]-a[4];
  cpx e2=a[2]+a[6], e3=a[2]-a[6];
  cpx f0=a[1]+a[5], f1=a[1]-a[5];
  cpx f2=a[3]+a[7], f3=a[3]-a[7];
  cpx ie3 = muli<SGN>(e3), if3 = muli<SGN>(f3);
  cpx E0=e0+e2, E2=e0-e2;
  cpx E1=e1+ie3, E3=e1-ie3;
  cpx O0=f0+f2, O2=f0-f2;
  cpx O1=f1+if3, O3=f1-if3;
  cpx O2r = muli<SGN>(O2);
  cpx O1r = cmulf(O1, mkc(C,  SC));
  cpx O3r = cmulf(O3, mkc(-C, SC));
  X[0]=E0+O0;  X[4]=E0-O0;
  X[1]=E1+O1r; X[5]=E1-O1r;
  X[2]=E2+O2r; X[6]=E2-O2r;
  X[3]=E3+O3r; X[7]=E3-O3r;
}

// W16^q = e^{-2pi i q/16}, q=0..7
__device__ __forceinline__ void w16_tab(cpx* W){
  W[0] = mkc( 1.f, 0.f);
  W[1] = mkc( 0.923879533f, -0.382683432f);
  W[2] = mkc( 0.707106781f, -0.707106781f);
  W[3] = mkc( 0.382683432f, -0.923879533f);
  W[4] = mkc( 0.f, -1.f);
  W[5] = mkc(-0.382683432f, -0.923879533f);
  W[6] = mkc(-0.707106781f, -0.707106781f);
  W[7] = mkc(-0.923879533f, -0.382683432f);
}

// W[q] = e^{i*ang*q}, q=1..7: one sincosf + 6 cmulf, dep depth 3 (was 6).
// Verified in v11's full pass (absmax 1.0).
__device__ __forceinline__ void wtree8(float ang, cpx* W){
  float sn, cn; __sincosf(ang, &sn, &cn);
  W[1] = mkc(cn, sn);
  W[2] = cmulf(W[1], W[1]);
  W[3] = cmulf(W[2], W[1]);
  W[4] = cmulf(W[2], W[2]);
  W[5] = cmulf(W[3], W[2]);
  W[6] = cmulf(W[3], W[3]);
  W[7] = cmulf(W[4], W[3]);
}

// first forward stage (t=1024): global reads at u+q*1024 (q<4; upper half is
// the zero padding), LDS writes at SW(u)+q*1024 — single base + immediates.
template<int T>
__device__ void dif8_first_g(cpx* S, const cpx* __restrict__ xb, int tid){
  const float ang = -6.283185307179586f / 8192.f;
  for (int u = tid; u < 1024; u += T){
    cpx* p = S + SW(u);
    cpx a[8], X[8];
#pragma unroll
    for (int q = 0; q < 4; q++) a[q] = xb[u + q*1024];
#pragma unroll
    for (int q = 4; q < 8; q++) a[q] = mkc(0.f, 0.f);
    cpx W[8]; wtree8(ang * (float)u, W);
    dft8<-1>(a, X);
#pragma unroll
    for (int q = 1; q < 8; q++) X[q] = cmulf(X[q], W[q]);
#pragma unroll
    for (int q = 0; q < 8; q++) p[q*1024] = X[q];
  }
}

// size-1024 fwd stage (t=128): 2 bases (q parity), immediate offsets.
template<int T>
__device__ void dif8_s1024(cpx* S, int tid){
  const float ang = -6.283185307179586f / 1024.f;
  for (int u = tid; u < 1024; u += T){
    int j = u & 127;
    int base = ((u - j) << 3) + j;
    cpx* pe = S + (base ^ ((j >> 4) & 7));
    cpx* po = S + ((base ^ ((j >> 4) & 7)) ^ 8);
    cpx a[8], X[8];
    a[0]=pe[0];   a[1]=po[128]; a[2]=pe[256]; a[3]=po[384];
    a[4]=pe[512]; a[5]=po[640]; a[6]=pe[768]; a[7]=po[896];
    cpx W[8]; wtree8(ang * (float)j, W);
    dft8<-1>(a, X);
#pragma unroll
    for (int q = 1; q < 8; q++) X[q] = cmulf(X[q], W[q]);
    pe[0]=X[0];   po[128]=X[1]; pe[256]=X[2]; po[384]=X[3];
    pe[512]=X[4]; po[640]=X[5]; pe[768]=X[6]; po[896]=X[7];
  }
}

// size-128 fwd stage (t=16): 8 addrs at 2 ops each, computed once & reused.
template<int T>
__device__ void dif8_s128(cpx* S, int tid){
  const float ang = -6.283185307179586f / 128.f;
  for (int u = tid; u < 1024; u += T){
    int j = u & 15;
    int base = ((u - j) << 3) + j;
    int B  = base & ~15;
    int jj = (base & 15) ^ ((base >> 4) & 8);
    int ad[8];
#pragma unroll
    for (int q = 0; q < 8; q++) ad[q] = B + (q << 4) + (jj ^ q);
    cpx a[8], X[8];
#pragma unroll
    for (int q = 0; q < 8; q++) a[q] = S[ad[q]];
    cpx W[8]; wtree8(ang * (float)j, W);
    dft8<-1>(a, X);
#pragma unroll
    for (int q = 1; q < 8; q++) X[q] = cmulf(X[q], W[q]);
#pragma unroll
    for (int q = 0; q < 8; q++) S[ad[q]] = X[q];
  }
}

// size-128 inv stage (t=16)
template<int T>
__device__ void dit8_s128(cpx* S, int tid){
  const float ang = 6.283185307179586f / 128.f;
  for (int u = tid; u < 1024; u += T){
    int j = u & 15;
    int base = ((u - j) << 3) + j;
    int B  = base & ~15;
    int jj = (base & 15) ^ ((base >> 4) & 8);
    int ad[8];
#pragma unroll
    for (int q = 0; q < 8; q++) ad[q] = B + (q << 4) + (jj ^ q);
    cpx a[8], X[8];
#pragma unroll
    for (int q = 0; q < 8; q++) a[q] = S[ad[q]];
    cpx W[8]; wtree8(ang * (float)j, W);
#pragma unroll
    for (int q = 1; q < 8; q++) a[q] = cmulf(a[q], W[q]);
    dft8<1>(a, X);
#pragma unroll
    for (int q = 0; q < 8; q++) S[ad[q]] = X[q];
  }
}

// size-1024 inv stage (t=128)
template<int T>
__device__ void dit8_s1024(cpx* S, int tid){
  const float ang = 6.283185307179586f / 1024.f;
  for (int u = tid; u < 1024; u += T){
    int j = u & 127;
    int base = ((u - j) << 3) + j;
    cpx* pe = S + (base ^ ((j >> 4) & 7));
    cpx* po = S + ((base ^ ((j >> 4) & 7)) ^ 8);
    cpx a[8], X[8];
    a[0]=pe[0];   a[1]=po[128]; a[2]=pe[256]; a[3]=po[384];
    a[4]=pe[512]; a[5]=po[640]; a[6]=pe[768]; a[7]=po[896];
    cpx W[8]; wtree8(ang * (float)j, W);
#pragma unroll
    for (int q = 1; q < 8; q++) a[q] = cmulf(a[q], W[q]);
    dft8<1>(a, X);
    pe[0]=X[0];   po[128]=X[1]; pe[256]=X[2]; po[384]=X[3];
    pe[512]=X[4]; po[640]=X[5]; pe[768]=X[6]; po[896]=X[7];
  }
}

// last inverse stage (t=1024): LDS reads at SW(u)+q*1024 (1 base, immediates),
// only q<4 outputs written DIRECTLY to global (coalesced).
template<int T>
__device__ void dit8_last_g(cpx* S, cpx* __restrict__ yb, int tid){
  const float ang = 6.283185307179586f / 8192.f;
  for (int u = tid; u < 1024; u += T){
    cpx* p = S + SW(u);
    cpx a[8], X[8];
#pragma unroll
    for (int q = 0; q < 8; q++) a[q] = p[q*1024];
    cpx W[8]; wtree8(ang * (float)u, W);
#pragma unroll
    for (int q = 1; q < 8; q++) a[q] = cmulf(a[q], W[q]);
    dft8<1>(a, X);
#pragma unroll
    for (int q = 0; q < 4; q++) yb[u + q*1024] = X[q];
  }
}

// merged dif8(size=16) + r2: thread v owns block [16v,16v+16); odd address =
// even address ^ 1; addresses computed once & reused. (v9-verified)
template<int T>
__device__ void fwd_tail16(cpx* S, int tid){
  cpx W[8]; w16_tab(W);
  for (int v = tid; v < 512; v += T){
    const int base = v << 4;
    const int sw = v & 15;
    int ae[8];
#pragma unroll
    for (int q = 0; q < 8; q++) ae[q] = base + ((2*q) ^ sw);
    cpx a0[8], a1[8], X0[8], X1[8];
#pragma unroll
    for (int q = 0; q < 8; q++){
      a0[q] = S[ae[q]];
      a1[q] = S[ae[q] ^ 1];
    }
    dft8<-1>(a0, X0);
    dft8<-1>(a1, X1);
#pragma unroll
    for (int q = 0; q < 8; q++){
      cpx tq = cmulf(X1[q], W[q]);          // j=1 twiddle (const)
      S[ae[q]]     = X0[q] + tq;            // r2 sum
      S[ae[q] ^ 1] = X0[q] - tq;            // r2 diff
    }
  }
}

// merged r2 + dit8(size=16)  (v9-verified)
template<int T>
__device__ void inv_head16(cpx* S, int tid){
  cpx W[8]; w16_tab(W);
  for (int v = tid; v < 512; v += T){
    const int base = v << 4;
    const int sw = v & 15;
    int ae[8];
#pragma unroll
    for (int q = 0; q < 8; q++) ae[q] = base + ((2*q) ^ sw);
    cpx p0[8], p1[8], X0[8], X1[8];
#pragma unroll
    for (int q = 0; q < 8; q++){
      cpx e = S[ae[q]];
      cpx o = S[ae[q] ^ 1];
      p0[q] = e + o;
      p1[q] = cmulcf(e - o, W[q]);
    }
    dft8<1>(p0, X0);
    dft8<1>(p1, X1);
#pragma unroll
    for (int q = 0; q < 8; q++){
      S[ae[q]]     = X0[q];
      S[ae[q] ^ 1] = X1[q];
    }
  }
}

// sigma for radices (8,8,8,8,2) — verified
__device__ __forceinline__ int sig8192(int k){
  return ((k & 7) << 10) | (((k >> 3) & 7) << 7) | (((k >> 6) & 7) << 4)
       | (((k >> 9) & 7) << 1) | ((k >> 12) & 1);
}
__device__ __forceinline__ int siginv_even(int m){  // k such that sig8192(k) == 2m
  return (m >> 9) | (((m >> 6) & 7) << 3) | (((m >> 3) & 7) << 6) | ((m & 7) << 9);
}

__device__ __forceinline__ double wsum64(double v){
#pragma unroll
  for (int m = 32; m > 0; m >>= 1) v += __shfl_xor(v, m, 64);
  return v;
}

// A) wave-per-l Cauchy (fp64) -> Hermitian-forced Y[0..8191]; T via WGs>=1025
#define KHAT_CAUCHY_WGS 1025
__global__ __launch_bounds__(256) void s4_khat_kernel(const float* __restrict__ Bp,
                                                      const float* __restrict__ Cp,
                                                      double2* __restrict__ Y,
                                                      double* __restrict__ T){
  const double PI = 3.14159265358979323846264338327950288;
  const int bid = blockIdx.x;
  const int tid = threadIdx.x;
  if (bid >= KHAT_CAUCHY_WGS){
    int d = (bid - KHAT_CAUCHY_WGS) * 256 + tid;
    double phi = PI * (double)(2*d - 1) / 16384.0;
    double s, c; sincos(phi, &s, &c);
    T[d] = c / s;
    return;
  }
  const int l = bid * 4 + (tid >> 6);     // one wave per bin l
  const int n = tid & 63;                 // lane owns pole n
  if (l > 4096) return;
  double th = (2.0 * PI / 8192.0) * (double)l;
  double wr = cos(th), wi = sin(th);
  double ux = 1.0 + wr, uy = wi;
  double vx = 1.0 - wr, vy = -wi;
  double gx = 20.0 * vx, gy = 20.0 * vy;
  double Bn = (double)Bp[n], Cn = (double)Cp[n];
  double Pn = sqrt((double)n + 0.5);
  double lx = -0.5, ly = PI * (double)n;
  double dx = gx - (ux*lx - uy*ly);
  double dy = gy - (ux*ly + uy*lx);
  double inv2 = 2.0 / (dx*dx + dy*dy);
  double cix = dx * inv2, ciy = -dy * inv2;
  double w00 = Cn*Bn, w01 = Cn*Pn, w10 = Pn*Bn, w11 = Pn*Pn;
  double s00x = wsum64(w00*cix), s00y = wsum64(w00*ciy);
  double s01x = wsum64(w01*cix), s01y = wsum64(w01*ciy);
  double s10x = wsum64(w10*cix), s10y = wsum64(w10*ciy);
  double s11x = wsum64(w11*cix), s11y = wsum64(w11*ciy);
  double hux = 0.5*ux, huy = 0.5*uy;
  double k11x = hux*s11x - huy*s11y;
  double k11y = hux*s11y + huy*s11x;
  double p1x = 1.0 + k11x, p1y = k11y;
  double t1x = s01x*p1x - s01y*p1y, t1y = s01x*p1y + s01y*p1x;
  double t2x = t1x*s10x - t1y*s10y, t2y = t1x*s10y + t1y*s10x;
  double crx = t2x*hux - t2y*huy,   cry = t2x*huy + t2y*hux;
  double vr = s00x - crx, vi = s00y - cry;
  if (n == 0){
    if (l == 0 || l == 4096) Y[l] = make_double2(vr, 0.0);
    else                     Y[l] = make_double2(vr, vi);
  } else if (n == 1 && l != 0 && l != 4096){
    Y[8192 - l] = make_double2(vr, -vi);
  }
}

// B) LDS-staged Dirichlet odd bins + S_K + table writes — v4/v9 form, verified
__global__ __launch_bounds__(256) void s4_tabs_kernel(const double2* __restrict__ Y,
                                                      const double* __restrict__ T,
                                                      float2* __restrict__ Ta,
                                                      float2* __restrict__ Tb){
  __shared__ __align__(16) float2 Ys[8192];
  const int tid = threadIdx.x;
  const int g   = blockIdx.x;        // 0..511
  const int lA  = g * 4;
  const int lB  = 4092 - lA;
  double skr = 0.0, ski = 0.0;
  for (int m = tid; m < 8192; m += 256){
    double2 v = Y[m];
    skr += v.x; ski += v.y;
    Ys[m] = make_float2((float)v.x, (float)v.y);
  }
  __syncthreads();
  double aAr[4]={0,0,0,0}, aAi[4]={0,0,0,0};
  double aBr[4]={0,0,0,0}, aBi[4]={0,0,0,0};
#pragma unroll 4
  for (int s = 0; s < 32; s++){
    const int d = (s << 8) + tid;
    const double t = T[d];
#pragma unroll
    for (int j = 0; j < 4; j++){
      float2 va = Ys[(lA + j + d) & 8191];
      float2 vb = Ys[(lB + j + d) & 8191];
      aAr[j] += t * (double)va.x;  aAi[j] += t * (double)va.y;
      aBr[j] += t * (double)vb.x;  aBi[j] += t * (double)vb.y;
    }
  }
  __syncthreads();
  double2 (*red)[9] = (double2 (*)[9])(void*)Ys;
#pragma unroll
  for (int j = 0; j < 4; j++){
    red[tid][j]     = make_double2(aAr[j], aAi[j]);
    red[tid][4 + j] = make_double2(aBr[j], aBi[j]);
  }
  red[tid][8] = make_double2(skr, ski);
  __syncthreads();
  for (int h = 128; h > 0; h >>= 1){
    if (tid < h){
#pragma unroll
      for (int j = 0; j < 9; j++){
        red[tid][j].x += red[tid + h][j].x;
        red[tid][j].y += red[tid + h][j].y;
      }
    }
    __syncthreads();
  }
  if (tid < 4){
    const int l = lA + tid;
    const double SKr = red[0][8].x, SKi = red[0][8].y;
    const double Por = red[0][tid].x, Poi = red[0][tid].y;
    const double Pmr = red[0][4 + (3 - tid)].x, Pmi = red[0][4 + (3 - tid)].y;
    const double q = (1.0/8192.0) * (1.0/8192.0);
    int mo = sig8192(2*l + 1) >> 1;
    Ta[mo] = make_float2((float)((SKr - Poi) * q), (float)((SKi + Por) * q));
    Tb[mo] = make_float2((float)((SKr - Pmi) * q), (float)((SKi + Pmr) * q));
    const double sc = 1.0/8192.0;
    int me = sig8192(2*l) >> 1;
    double2 ye = Y[l];
    double2 yo = Y[4096 - l];
    Ta[me] = make_float2((float)(ye.x * sc), (float)(ye.y * sc));
    Tb[me] = make_float2((float)(yo.x * sc), (float)(yo.y * sc));
  }
  if (g == 0 && tid == 4){
    double2 yn = Y[2048];
    float2 v = make_float2((float)(yn.x / 8192.0), (float)(yn.y / 8192.0));
    Ta[4096] = v; Tb[4096] = v;
  }
}

// C) conv v13 — v9 structure + wtree8; inline pointwise (v9-verified).
__global__ __launch_bounds__(TPB, 4) void s4_conv_kernel(const cpx* __restrict__ x2,
                                                         const cpx* __restrict__ Ta,
                                                         const cpx* __restrict__ Tb,
                                                         cpx* __restrict__ y2){
  __shared__ __align__(16) cpx S[8192];
  const int tid = threadIdx.x;
  const int b = blockIdx.x;
  const cpx* xb = x2 + (size_t)b * 4096;
  dif8_first_g<TPB>(S, xb, tid);  __syncthreads();
  dif8_s1024<TPB>(S, tid);        __syncthreads();
  dif8_s128<TPB>(S, tid);         __syncthreads();
  fwd_tail16<TPB>(S, tid);        __syncthreads();
  for (int m = tid; m < 4097; m += TPB){
    int s, k;
    if (m == 4096){ s = 1; k = 4096; }
    else          { s = 2*m; k = siginv_even(m); }
    int j = (8192 - k) & 8191;
    int sj = sig8192(j);
    int as = SW(s), aj = SW(sj);
    cpx Zk = S[as], Zj = S[aj];
    cpx cZj = mkc(Zj.x, -Zj.y);
    cpx A  = 0.5f * (Zk + cZj);
    cpx Bc = 0.5f * (Zk - cZj);
    float sn, cn; __sincosf(-3.834951969714103e-4f * (float)k, &sn, &cn);
    cpx tb = cmulf(mkc(cn, sn), Bc);
    // tcb == conj(tb) exactly (same partial products) — folded.
    cpx Xk = mkc(A.x + tb.y,  A.y - tb.x);
    cpx Xm = mkc(A.x - tb.y, -A.y - tb.x);
    cpx Yk = cmulf(Xk, Ta[m]);
    cpx Ym = cmulf(Xm, Tb[m]);
    cpx cYm = mkc(Ym.x, -Ym.y);
    cpx E = 0.5f * (Yk + cYm);
    cpx D = 0.5f * (Yk - cYm);
    cpx Od = cmulf(mkc(cn, -sn), D);
    S[as] = mkc(E.x - Od.y, E.y + Od.x);
    if (aj != as)
      S[aj] = mkc(E.x + Od.y, Od.x - E.y);
  }
  __syncthreads();
  inv_head16<TPB>(S, tid);        __syncthreads();
  dit8_s128<TPB>(S, tid);         __syncthreads();
  dit8_s1024<TPB>(S, tid);        __syncthreads();
  cpx* yb = y2 + (size_t)b * 4096;
  dit8_last_g<TPB>(S, yb, tid);
}

extern "C" void kernel_launch(void* const* d_in, const int* in_sizes, int n_in,
                              void* d_out, int out_size, void* d_ws, size_t ws_size,
                              hipStream_t stream){
  (void)n_in; (void)out_size; (void)ws_size;
  const float* x  = (const float*)d_in[0];
  const float* Bp = (const float*)d_in[1];
  const float* Cp = (const float*)d_in[2];
  // ws: Y[8192] double2 @0 (128K), T[8192] double @131072 (64K),
  //     Ta[4097] float2 @196608, Tb[4097] float2 @229632  (~257 KB)
  double2* Yt = (double2*)d_ws;
  double*  Tt = (double*)((char*)d_ws + 131072);
  float2*  Ta = (float2*)((char*)d_ws + 196608);
  float2*  Tb = (float2*)((char*)d_ws + 229632);
  const int batch = in_sizes[0] / 8192;
  hipLaunchKernelGGL(s4_khat_kernel, dim3(KHAT_CAUCHY_WGS + 32), dim3(256), 0, stream,
                     Bp, Cp, Yt, Tt);
  hipLaunchKernelGGL(s4_tabs_kernel, dim3(512), dim3(256), 0, stream, Yt, Tt, Ta, Tb);
  hipLaunchKernelGGL(s4_conv_kernel, dim3(batch), dim3(TPB), 0, stream,
                     (const cpx*)x, (const cpx*)Ta, (const cpx*)Tb, (cpx*)d_out);
}